// Round 10
// baseline (140.567 us; speedup 1.0000x reference)
//
#include <hip/hip_runtime.h>
#include <hip/hip_bf16.h>
#include <cstdint>

#define NPOS 512
#define NNEG 512
#define BATCH 8
#define DDIM 128
#define NLEM 32768
#define NX_ELEM (BATCH * (NPOS + NNEG) * DDIM)  // 1048576
#define NM_ELEM (NLEM * DDIM)                   // 4194304

typedef __attribute__((ext_vector_type(4))) float f32x4;
typedef __attribute__((ext_vector_type(16))) float f32x16;
typedef __attribute__((ext_vector_type(8))) short short8;

__device__ __forceinline__ unsigned short f2bf(float f) {
  unsigned u = __float_as_uint(f);
  u = (u + 0x7FFFu + ((u >> 16) & 1u)) >> 16;
  return (unsigned short)u;
}

__device__ __forceinline__ short8 cvt8(f32x4 a0, f32x4 a1) {
  short8 w;
  w[0] = (short)f2bf(a0[0]); w[1] = (short)f2bf(a0[1]);
  w[2] = (short)f2bf(a0[2]); w[3] = (short)f2bf(a0[3]);
  w[4] = (short)f2bf(a1[0]); w[5] = (short)f2bf(a1[1]);
  w[6] = (short)f2bf(a1[2]); w[7] = (short)f2bf(a1[3]);
  return w;
}

__device__ __forceinline__ void async16(const void* g, void* l) {
  __builtin_amdgcn_global_load_lds(
      (const __attribute__((address_space(1))) unsigned int*)g,
      (__attribute__((address_space(3))) unsigned int*)l, 16, 0, 0);
}

// ---- full newmem row (used by prep for pos rows & by fallback) ----
__device__ __forceinline__ void newmem_row(int r, int lane, const float* __restrict__ X,
                                           const int* __restrict__ vis,
                                           const float* __restrict__ Mem, int start,
                                           float* __restrict__ out) {
  const int d0 = lane, d1 = lane + 64;
  float v0, v1;
  if (r < NPOS) {
    const float s0 = Mem[(size_t)r * DDIM + d0];
    const float s1 = Mem[(size_t)r * DDIM + d1];
    float a0 = 0.f, a1 = 0.f;
#pragma unroll
    for (int b = 0; b < BATCH; ++b) {
      const float w = (float)vis[b * NPOS + r];
      const float* px = X + (size_t)(b * (NPOS + NNEG) + r) * DDIM;
      a0 += w * px[d0];
      a1 += w * px[d1];
    }
    v0 = 0.5f * s0 + 0.0625f * a0;
    v1 = 0.5f * s1 + 0.0625f * a1;
  } else if (r >= start && r < start + BATCH * NNEG) {
    const int q = r - start;
    const int b = q >> 9, n = q & 511;
    const float* px = X + (size_t)(b * (NPOS + NNEG) + NPOS + n) * DDIM;
    v0 = px[d0];
    v1 = px[d1];
  } else {
    v0 = Mem[(size_t)r * DDIM + d0];
    v1 = Mem[(size_t)r * DDIM + d1];
  }
  float s = v0 * v0 + v1 * v1;
#pragma unroll
  for (int off = 32; off; off >>= 1) s += __shfl_xor(s, off, 64);
  const float inv = 1.0f / fmaxf(sqrtf(s), 1e-12f);
  out[(size_t)r * DDIM + d0] = v0 * inv;
  out[(size_t)r * DDIM + d1] = v1 * inv;
}

// ==== prep: convert all x + all memory, y, pos newmem rows only ====
// blocks: [0,512) x | [512,2560) mem | [2560,2576) y | [2576,2704) pos newmem
__global__ __launch_bounds__(256) void prep_kernel(
    const float* __restrict__ X, const int* __restrict__ y,
    const int* __restrict__ vis, const float* __restrict__ Mem,
    const int* __restrict__ lru_p, unsigned short* __restrict__ xb,
    unsigned short* __restrict__ mb, float* __restrict__ out_y,
    float* __restrict__ out_mem) {
  const int blk = blockIdx.x;
  if (blk < 512) {
    const size_t i = ((size_t)blk * 256 + threadIdx.x) * 8;
    *(short8*)(xb + i) = cvt8(*(const f32x4*)(X + i), *(const f32x4*)(X + i + 4));
  } else if (blk < 2560) {
    const size_t i = ((size_t)(blk - 512) * 256 + threadIdx.x) * 8;
    *(short8*)(mb + i) = cvt8(*(const f32x4*)(Mem + i), *(const f32x4*)(Mem + i + 4));
  } else if (blk < 2576) {
    const int i = (blk - 2560) * 256 + threadIdx.x;
    out_y[i] = (float)y[i];
  } else {
    const int r = (blk - 2576) * 4 + (threadIdx.x >> 6);  // 0..511 pos rows
    const int start = NPOS + lru_p[0] * (NNEG * BATCH);
    newmem_row(r, threadIdx.x & 63, X, vis, Mem, start, out_mem);
  }
}

__device__ __forceinline__ void hoist_b(const short* Btile, short8 bfr[8][2],
                                        int wc, int la, int lb) {
#pragma unroll
  for (int kk = 0; kk < 8; ++kk)
#pragma unroll
    for (int n2 = 0; n2 < 2; ++n2) {
      const int row = wc * 64 + n2 * 32 + la;
      const int ss = ((kk * 2 + lb) ^ (row & 15)) * 8;
      bfr[kk][n2] = *(const short8*)&Btile[row * 128 + ss];
    }
}

__device__ __forceinline__ void tile_mfma(const short* Atile, const short8 bfr[8][2],
                                          f32x16 acc[2][2], int wr, int la, int lb) {
#pragma unroll
  for (int kk = 0; kk < 8; ++kk) {
    short8 af[2];
#pragma unroll
    for (int m2 = 0; m2 < 2; ++m2) {
      const int row = wr * 64 + m2 * 32 + la;
      const int ss = ((kk * 2 + lb) ^ (row & 15)) * 8;
      af[m2] = *(const short8*)&Atile[row * 128 + ss];
    }
#pragma unroll
    for (int m2 = 0; m2 < 2; ++m2)
#pragma unroll
      for (int n2 = 0; n2 < 2; ++n2)
        acc[m2][n2] = __builtin_amdgcn_mfma_f32_32x32x16_bf16(
            af[m2], bfr[kk][n2], acc[m2][n2], 0, 0, 0);
  }
}

__device__ __forceinline__ void store_acc(const f32x16 acc[2][2],
                                          float* __restrict__ C, int ldc, int m0,
                                          int n0c, int wr, int wc, int la, int lb) {
#pragma unroll
  for (int m2 = 0; m2 < 2; ++m2)
#pragma unroll
    for (int n2 = 0; n2 < 2; ++n2) {
      const int col = n0c + wc * 64 + n2 * 32 + la;
      const int rbase = m0 + wr * 64 + m2 * 32 + lb * 4;
#pragma unroll
      for (int r = 0; r < 16; ++r) {
        const int row = rbase + (r & 3) + 8 * (r >> 2);
        C[(size_t)row * ldc + col] = acc[m2][n2][r];
      }
    }
}

// ==== half-band persistent GEMM (exact R8) + barrier-free newmem tail ====
// Block blk: band = blk>>1 (cols), h = blk&1 -> sim row panels K = h*16+0..15.
// B staged once through ldsA[1] (bf16 DMA), hoisted to regs.
// Blocks 0..127: one noise tile after the sim loop.
// Tail: rows r = 512 + idx*512 + blk (idx = i*4+wv < 63) -> copy/normalize,
// software-pipelined, no barriers (hides under other blocks' store drains).
__global__ __launch_bounds__(256, 2) void gemm_band2_kernel(
    const unsigned short* __restrict__ Xb, const unsigned short* __restrict__ Mb,
    const float* __restrict__ X, const float* __restrict__ Mem,
    const int* __restrict__ lru_p, float* __restrict__ Csim,
    float* __restrict__ Cnoise, float* __restrict__ out_mem) {
  __shared__ short ldsA[2][128 * 128];  // exactly 64 KB

  const int t = threadIdx.x;
  const int lane = t & 63, wv = t >> 6;
  const int rl = lane >> 4, slot = lane & 15;
  const int wr = wv >> 1, wc = wv & 1;
  const int la = lane & 31, lb = lane >> 5;
  const int blk = blockIdx.x;
  const int band = blk >> 1, h = blk & 1;
  const int n0 = band * 128;

  auto stage_tile = [&](short* dst, const unsigned short* src, int rowbase) {
#pragma unroll
    for (int i = 0; i < 8; ++i) {
      const int rowb = wv * 32 + i * 4;  // wave-uniform base row
      const int row = rowb + rl;
      const int ss = slot ^ (row & 15);  // inverse-swizzled source (involution)
      async16(src + (size_t)(rowbase + row) * DDIM + ss * 8, &dst[rowb * 128]);
    }
  };

  // ---- prologue: B through ldsA[1]; first A panel into ldsA[0] ----
  stage_tile(ldsA[1], Mb, n0);
  {
    const int K0 = h * 16;
    stage_tile(ldsA[0], Xb, (K0 >> 2) * 1024 + (K0 & 3) * 128);
  }
  asm volatile("s_waitcnt vmcnt(0)" ::: "memory");
  __builtin_amdgcn_s_barrier();
  __builtin_amdgcn_sched_barrier(0);

  short8 bfr[8][2];
  hoist_b(ldsA[1], bfr, wc, la, lb);  // B -> 32 VGPR
  asm volatile("s_waitcnt lgkmcnt(0)" ::: "memory");
  __builtin_amdgcn_s_barrier();
  __builtin_amdgcn_sched_barrier(0);

  int p = 0;
  for (int k = 0; k < 16; ++k) {
    if (k + 1 < 16) {
      const int K = h * 16 + k + 1;
      stage_tile(ldsA[p ^ 1], Xb, (K >> 2) * 1024 + (K & 3) * 128);
    }

    f32x16 acc[2][2] = {};
    tile_mfma(ldsA[p], bfr, acc, wr, la, lb);
    store_acc(acc, Csim, NLEM, (h * 16 + k) * 128, n0, wr, wc, la, lb);

    // vmcnt(60) < 64 stores issued after the 8 staging loads => loads
    // retired; ~60 stores keep draining across the barrier.
    asm volatile("s_waitcnt vmcnt(60)" ::: "memory");
    __builtin_amdgcn_s_barrier();
    __builtin_amdgcn_sched_barrier(0);
    p ^= 1;
  }

  // ---- noise tail: blocks 0..127 each do one 128x128 noise tile ----
  if (blk < 128) {
    const int rp = blk >> 2, cb = blk & 3;  // row panel 0..31, col band 0..3
    stage_tile(ldsA[p ^ 1], Xb, (rp >> 2) * 1024 + 512 + (rp & 3) * 128);
    stage_tile(ldsA[p], Mb, cb * 128);
    asm volatile("s_waitcnt vmcnt(0)" ::: "memory");
    __builtin_amdgcn_s_barrier();
    __builtin_amdgcn_sched_barrier(0);
    short8 bfr2[8][2];
    hoist_b(ldsA[p], bfr2, wc, la, lb);
    f32x16 acc[2][2] = {};
    tile_mfma(ldsA[p ^ 1], bfr2, acc, wr, la, lb);
    store_acc(acc, Cnoise, NPOS, rp * 128, cb * 128, wr, wc, la, lb);
  }

  // ---- newmem tail (barrier-free, 1-deep pipelined) ----
  // rows r = 512 + idx*512 + blk, idx = i*4 + wv in [0,63): copy + normalize.
  {
    const int nm_start = NPOS + lru_p[0] * (NNEG * BATCH);
    auto row_ptr = [&](int idx) -> const float* {
      const int r = 512 + idx * 512 + blk;
      if (r >= nm_start && r < nm_start + BATCH * NNEG) {
        const int q = r - nm_start;
        return X + (size_t)((q >> 9) * (NPOS + NNEG) + NPOS + (q & 511)) * DDIM;
      }
      return Mem + (size_t)r * DDIM;
    };

    int idx = wv;
    float c0 = 0.f, c1 = 0.f;
    {
      const float* pr = row_ptr(idx);  // idx = wv < 63 always
      c0 = pr[lane];
      c1 = pr[lane + 64];
    }
#pragma unroll 1
    for (int i = 0; i < 16; ++i) {
      const int nidx = idx + 4;
      float q0 = 0.f, q1 = 0.f;
      if (i + 1 < 16 && nidx < 63) {  // prefetch next row
        const float* pr = row_ptr(nidx);
        q0 = pr[lane];
        q1 = pr[lane + 64];
      }
      if (idx < 63) {
        const int r = 512 + idx * 512 + blk;
        float s = c0 * c0 + c1 * c1;
#pragma unroll
        for (int off = 32; off; off >>= 1) s += __shfl_xor(s, off, 64);
        const float inv = 1.0f / fmaxf(sqrtf(s), 1e-12f);
        out_mem[(size_t)r * DDIM + lane] = c0 * inv;
        out_mem[(size_t)r * DDIM + lane + 64] = c1 * inv;
      }
      c0 = q0;
      c1 = q1;
      idx = nidx;
    }
  }
}

// ================= fallback path (used only if ws too small) ====
__global__ __launch_bounds__(256) void gemm_conv_kernel(
    const float* __restrict__ X, const float* __restrict__ Bm,
    float* __restrict__ C, int ldc, int a_off) {
  __shared__ short lds[2 * 128 * 128];
  short* ldsA = lds;
  short* ldsB = lds + 128 * 128;
  const int t = threadIdx.x;
  const int m0 = blockIdx.x * 128;
  const int n0 = blockIdx.y * 128;
  const int slot = t & 15;
  const int rsub = t >> 4;
#pragma unroll
  for (int it = 0; it < 8; ++it) {
    const int row = it * 16 + rsub;
    const int gr = m0 + row;
    const int xrow = ((gr >> 9) << 10) + (gr & 511) + a_off;
    const f32x4* pa = (const f32x4*)(X + (size_t)xrow * DDIM + slot * 8);
    const f32x4* pb = (const f32x4*)(Bm + (size_t)(n0 + row) * DDIM + slot * 8);
    short8 wa = cvt8(pa[0], pa[1]);
    short8 wb = cvt8(pb[0], pb[1]);
    const int ss = (slot ^ (row & 15)) * 8;
    *(short8*)&ldsA[row * 128 + ss] = wa;
    *(short8*)&ldsB[row * 128 + ss] = wb;
  }
  __syncthreads();
  const int lane = t & 63;
  const int wv = t >> 6;
  const int wr = wv >> 1, wc = wv & 1;
  const int la = lane & 31, lb = lane >> 5;
  short8 bfr[8][2];
  hoist_b(ldsB, bfr, wc, la, lb);
  f32x16 acc[2][2] = {};
  tile_mfma(ldsA, bfr, acc, wr, la, lb);
  store_acc(acc, C, ldc, m0, n0, wr, wc, la, lb);
}

__global__ void y_kernel(const int* __restrict__ y, float* __restrict__ out) {
  const int i = blockIdx.x * blockDim.x + threadIdx.x;
  if (i < BATCH * NPOS) out[i] = (float)y[i];
}

__global__ __launch_bounds__(256) void newmem_kernel(
    const float* __restrict__ X, const int* __restrict__ vis,
    const float* __restrict__ Mem, const int* __restrict__ lru_p,
    float* __restrict__ out) {
  const int r = blockIdx.x * 4 + (threadIdx.x >> 6);
  const int start = NPOS + lru_p[0] * (NNEG * BATCH);
  newmem_row(r, threadIdx.x & 63, X, vis, Mem, start, out);
}

extern "C" void kernel_launch(void* const* d_in, const int* in_sizes, int n_in,
                              void* d_out, int out_size, void* d_ws, size_t ws_size,
                              hipStream_t stream) {
  const float* x = (const float*)d_in[0];
  const int* y = (const int*)d_in[1];
  const int* visible = (const int*)d_in[2];
  const float* memory = (const float*)d_in[3];
  const int* lru = (const int*)d_in[4];
  float* out = (float*)d_out;

  const size_t OFF_Y = (size_t)BATCH * NPOS * NLEM;
  const size_t OFF_NOISE = OFF_Y + (size_t)BATCH * NPOS;
  const size_t OFF_MEM = OFF_NOISE + (size_t)BATCH * NNEG * NPOS;

  const size_t need = (size_t)(NX_ELEM + NM_ELEM) * 2;  // 10.5 MB bf16 scratch
  if (ws_size >= need) {
    unsigned short* xb = (unsigned short*)d_ws;
    unsigned short* mb = xb + NX_ELEM;
    prep_kernel<<<2704, 256, 0, stream>>>(
        x, y, visible, memory, lru, xb, mb, out + OFF_Y, out + OFF_MEM);
    gemm_band2_kernel<<<512, 256, 0, stream>>>(xb, mb, x, memory, lru, out,
                                               out + OFF_NOISE, out + OFF_MEM);
  } else {
    gemm_conv_kernel<<<dim3(32, 256), 256, 0, stream>>>(x, memory, out, NLEM, 0);
    gemm_conv_kernel<<<dim3(32, 4), 256, 0, stream>>>(x, memory, out + OFF_NOISE, NPOS, NPOS);
    y_kernel<<<16, 256, 0, stream>>>(y, out + OFF_Y);
    newmem_kernel<<<NLEM / 4, 256, 0, stream>>>(x, visible, memory, lru, out + OFF_MEM);
  }
}

// Round 11
// 123.553 us; speedup vs baseline: 1.1377x; 1.1377x over previous
//
#include <hip/hip_runtime.h>
#include <hip/hip_bf16.h>
#include <cstdint>

#define NPOS 512
#define NNEG 512
#define BATCH 8
#define DDIM 128
#define NLEM 32768
#define NX_ELEM (BATCH * (NPOS + NNEG) * DDIM)  // 1048576

typedef __attribute__((ext_vector_type(4))) float f32x4;
typedef __attribute__((ext_vector_type(16))) float f32x16;
typedef __attribute__((ext_vector_type(8))) short short8;

__device__ __forceinline__ unsigned short f2bf(float f) {
  unsigned u = __float_as_uint(f);
  u = (u + 0x7FFFu + ((u >> 16) & 1u)) >> 16;
  return (unsigned short)u;
}

__device__ __forceinline__ short8 cvt8(f32x4 a0, f32x4 a1) {
  short8 w;
  w[0] = (short)f2bf(a0[0]); w[1] = (short)f2bf(a0[1]);
  w[2] = (short)f2bf(a0[2]); w[3] = (short)f2bf(a0[3]);
  w[4] = (short)f2bf(a1[0]); w[5] = (short)f2bf(a1[1]);
  w[6] = (short)f2bf(a1[2]); w[7] = (short)f2bf(a1[3]);
  return w;
}

__device__ __forceinline__ void async16(const void* g, void* l) {
  __builtin_amdgcn_global_load_lds(
      (const __attribute__((address_space(1))) unsigned int*)g,
      (__attribute__((address_space(3))) unsigned int*)l, 16, 0, 0);
}

// ---- full newmem row (one wave per row, exact f32) ----
__device__ __forceinline__ void newmem_row(int r, int lane, const float* __restrict__ X,
                                           const int* __restrict__ vis,
                                           const float* __restrict__ Mem, int start,
                                           float* __restrict__ out) {
  const int d0 = lane, d1 = lane + 64;
  float v0, v1;
  if (r < NPOS) {
    const float s0 = Mem[(size_t)r * DDIM + d0];
    const float s1 = Mem[(size_t)r * DDIM + d1];
    float a0 = 0.f, a1 = 0.f;
#pragma unroll
    for (int b = 0; b < BATCH; ++b) {
      const float w = (float)vis[b * NPOS + r];
      const float* px = X + (size_t)(b * (NPOS + NNEG) + r) * DDIM;
      a0 += w * px[d0];
      a1 += w * px[d1];
    }
    v0 = 0.5f * s0 + 0.0625f * a0;
    v1 = 0.5f * s1 + 0.0625f * a1;
  } else if (r >= start && r < start + BATCH * NNEG) {
    const int q = r - start;
    const int b = q >> 9, n = q & 511;
    const float* px = X + (size_t)(b * (NPOS + NNEG) + NPOS + n) * DDIM;
    v0 = px[d0];
    v1 = px[d1];
  } else {
    v0 = Mem[(size_t)r * DDIM + d0];
    v1 = Mem[(size_t)r * DDIM + d1];
  }
  float s = v0 * v0 + v1 * v1;
#pragma unroll
  for (int off = 32; off; off >>= 1) s += __shfl_xor(s, off, 64);
  const float inv = 1.0f / fmaxf(sqrtf(s), 1e-12f);
  out[(size_t)r * DDIM + d0] = v0 * inv;
  out[(size_t)r * DDIM + d1] = v1 * inv;
}

// ==== prep: x-convert + y + ALL newmem rows (no mem-convert pass) ====
// blocks: [0,512) x | [512,528) y | [528,8720) newmem (4 rows/blk)
__global__ __launch_bounds__(256) void prep_kernel(
    const float* __restrict__ X, const int* __restrict__ y,
    const int* __restrict__ vis, const float* __restrict__ Mem,
    const int* __restrict__ lru_p, unsigned short* __restrict__ xb,
    float* __restrict__ out_y, float* __restrict__ out_mem) {
  const int blk = blockIdx.x;
  if (blk < 512) {
    const size_t i = ((size_t)blk * 256 + threadIdx.x) * 8;
    *(short8*)(xb + i) = cvt8(*(const f32x4*)(X + i), *(const f32x4*)(X + i + 4));
  } else if (blk < 528) {
    const int i = (blk - 512) * 256 + threadIdx.x;
    out_y[i] = (float)y[i];
  } else {
    const int r = (blk - 528) * 4 + (threadIdx.x >> 6);
    const int start = NPOS + lru_p[0] * (NNEG * BATCH);
    newmem_row(r, threadIdx.x & 63, X, vis, Mem, start, out_mem);
  }
}

__device__ __forceinline__ void hoist_b(const short* Btile, short8 bfr[8][2],
                                        int wc, int la, int lb) {
#pragma unroll
  for (int kk = 0; kk < 8; ++kk)
#pragma unroll
    for (int n2 = 0; n2 < 2; ++n2) {
      const int row = wc * 64 + n2 * 32 + la;
      const int ss = ((kk * 2 + lb) ^ (row & 15)) * 8;
      bfr[kk][n2] = *(const short8*)&Btile[row * 128 + ss];
    }
}

__device__ __forceinline__ void tile_mfma(const short* Atile, const short8 bfr[8][2],
                                          f32x16 acc[2][2], int wr, int la, int lb) {
#pragma unroll
  for (int kk = 0; kk < 8; ++kk) {
    short8 af[2];
#pragma unroll
    for (int m2 = 0; m2 < 2; ++m2) {
      const int row = wr * 64 + m2 * 32 + la;
      const int ss = ((kk * 2 + lb) ^ (row & 15)) * 8;
      af[m2] = *(const short8*)&Atile[row * 128 + ss];
    }
#pragma unroll
    for (int m2 = 0; m2 < 2; ++m2)
#pragma unroll
      for (int n2 = 0; n2 < 2; ++n2)
        acc[m2][n2] = __builtin_amdgcn_mfma_f32_32x32x16_bf16(
            af[m2], bfr[kk][n2], acc[m2][n2], 0, 0, 0);
  }
}

__device__ __forceinline__ void store_acc(const f32x16 acc[2][2],
                                          float* __restrict__ C, int ldc, int m0,
                                          int n0c, int wr, int wc, int la, int lb) {
#pragma unroll
  for (int m2 = 0; m2 < 2; ++m2)
#pragma unroll
    for (int n2 = 0; n2 < 2; ++n2) {
      const int col = n0c + wc * 64 + n2 * 32 + la;
      const int rbase = m0 + wr * 64 + m2 * 32 + lb * 4;
#pragma unroll
      for (int r = 0; r < 16; ++r) {
        const int row = rbase + (r & 3) + 8 * (r >> 2);
        C[(size_t)row * ldc + col] = acc[m2][n2][r];
      }
    }
}

// convert 128 f32 rows starting at Mem row `rbase` into swizzled bf16 LDS tile
// (R9-proven mechanism)
__device__ __forceinline__ void convert_b_tile(const float* __restrict__ Mem,
                                               int rbase, short* dst, int t) {
  const int srow = t >> 1, scol = (t & 1) * 64, sslot0 = scol >> 3;
  f32x4 vb[16];
  const f32x4* pb = (const f32x4*)(Mem + (size_t)(rbase + srow) * DDIM + scol);
#pragma unroll
  for (int j = 0; j < 16; ++j) vb[j] = pb[j];
#pragma unroll
  for (int j = 0; j < 8; ++j) {
    short8 w = cvt8(vb[2 * j], vb[2 * j + 1]);
    const int ss = (sslot0 + j) ^ (srow & 15);
    *(short8*)&dst[srow * 128 + ss * 8] = w;
  }
}

// ==== half-band persistent GEMM, 2 blocks/CU (exact R8 loop) ====
// Block blk: band = blk>>1 (cols), h = blk&1 -> sim row panels K = h*16+0..15.
// B band converted from f32 Mem in the prologue (no mem-convert prep pass).
// Blocks 0..127 additionally compute one noise tile at the tail.
__global__ __launch_bounds__(256, 2) void gemm_band2_kernel(
    const unsigned short* __restrict__ Xb, const float* __restrict__ Mem,
    float* __restrict__ Csim, float* __restrict__ Cnoise) {
  __shared__ short ldsA[2][128 * 128];  // exactly 64 KB

  const int t = threadIdx.x;
  const int lane = t & 63, wv = t >> 6;
  const int rl = lane >> 4, slot = lane & 15;
  const int wr = wv >> 1, wc = wv & 1;
  const int la = lane & 31, lb = lane >> 5;
  const int blk = blockIdx.x;
  const int band = blk >> 1, h = blk & 1;
  const int n0 = band * 128;

  auto stage_tile = [&](short* dst, const unsigned short* src, int rowbase) {
#pragma unroll
    for (int i = 0; i < 8; ++i) {
      const int rowb = wv * 32 + i * 4;  // wave-uniform base row
      const int row = rowb + rl;
      const int ss = slot ^ (row & 15);  // inverse-swizzled source (involution)
      async16(src + (size_t)(rowbase + row) * DDIM + ss * 8, &dst[rowb * 128]);
    }
  };

  // ---- prologue: first A panel via DMA; B band converted from f32 ----
  {
    const int K0 = h * 16;
    stage_tile(ldsA[0], Xb, (K0 >> 2) * 1024 + (K0 & 3) * 128);
  }
  convert_b_tile(Mem, n0, ldsA[1], t);
  asm volatile("s_waitcnt vmcnt(0) lgkmcnt(0)" ::: "memory");
  __builtin_amdgcn_s_barrier();
  __builtin_amdgcn_sched_barrier(0);

  short8 bfr[8][2];
  hoist_b(ldsA[1], bfr, wc, la, lb);  // B -> 32 VGPR
  asm volatile("s_waitcnt lgkmcnt(0)" ::: "memory");
  __builtin_amdgcn_s_barrier();
  __builtin_amdgcn_sched_barrier(0);

  int p = 0;
  for (int k = 0; k < 16; ++k) {
    // stage next panel BEFORE this step's stores (counted-vmcnt guarantee)
    if (k + 1 < 16) {
      const int K = h * 16 + k + 1;
      stage_tile(ldsA[p ^ 1], Xb, (K >> 2) * 1024 + (K & 3) * 128);
    }

    f32x16 acc[2][2] = {};
    tile_mfma(ldsA[p], bfr, acc, wr, la, lb);
    store_acc(acc, Csim, NLEM, (h * 16 + k) * 128, n0, wr, wc, la, lb);

    // vmcnt(60) < 64 stores issued after the 8 staging loads => loads
    // retired; ~60 stores keep draining across the barrier.
    asm volatile("s_waitcnt vmcnt(60)" ::: "memory");
    __builtin_amdgcn_s_barrier();
    __builtin_amdgcn_sched_barrier(0);
    p ^= 1;
  }

  // ---- noise tail: blocks 0..127 each do one 128x128 noise tile ----
  if (blk < 128) {
    const int rp = blk >> 2, cb = blk & 3;  // row panel 0..31, col band 0..3
    stage_tile(ldsA[p ^ 1], Xb, (rp >> 2) * 1024 + 512 + (rp & 3) * 128);
    convert_b_tile(Mem, cb * 128, ldsA[p], t);
    asm volatile("s_waitcnt vmcnt(0) lgkmcnt(0)" ::: "memory");
    __builtin_amdgcn_s_barrier();
    __builtin_amdgcn_sched_barrier(0);
    short8 bfr2[8][2];
    hoist_b(ldsA[p], bfr2, wc, la, lb);
    f32x16 acc[2][2] = {};
    tile_mfma(ldsA[p ^ 1], bfr2, acc, wr, la, lb);
    store_acc(acc, Cnoise, NPOS, rp * 128, cb * 128, wr, wc, la, lb);
  }
}

// ================= fallback path (used only if ws too small) ====
__global__ __launch_bounds__(256) void gemm_conv_kernel(
    const float* __restrict__ X, const float* __restrict__ Bm,
    float* __restrict__ C, int ldc, int a_off) {
  __shared__ short lds[2 * 128 * 128];
  short* ldsA = lds;
  short* ldsB = lds + 128 * 128;
  const int t = threadIdx.x;
  const int m0 = blockIdx.x * 128;
  const int n0 = blockIdx.y * 128;
  const int slot = t & 15;
  const int rsub = t >> 4;
#pragma unroll
  for (int it = 0; it < 8; ++it) {
    const int row = it * 16 + rsub;
    const int gr = m0 + row;
    const int xrow = ((gr >> 9) << 10) + (gr & 511) + a_off;
    const f32x4* pa = (const f32x4*)(X + (size_t)xrow * DDIM + slot * 8);
    const f32x4* pb = (const f32x4*)(Bm + (size_t)(n0 + row) * DDIM + slot * 8);
    short8 wa = cvt8(pa[0], pa[1]);
    short8 wb = cvt8(pb[0], pb[1]);
    const int ss = (slot ^ (row & 15)) * 8;
    *(short8*)&ldsA[row * 128 + ss] = wa;
    *(short8*)&ldsB[row * 128 + ss] = wb;
  }
  __syncthreads();
  const int lane = t & 63;
  const int wv = t >> 6;
  const int wr = wv >> 1, wc = wv & 1;
  const int la = lane & 31, lb = lane >> 5;
  short8 bfr[8][2];
  hoist_b(ldsB, bfr, wc, la, lb);
  f32x16 acc[2][2] = {};
  tile_mfma(ldsA, bfr, acc, wr, la, lb);
  store_acc(acc, C, ldc, m0, n0, wr, wc, la, lb);
}

__global__ void y_kernel(const int* __restrict__ y, float* __restrict__ out) {
  const int i = blockIdx.x * blockDim.x + threadIdx.x;
  if (i < BATCH * NPOS) out[i] = (float)y[i];
}

__global__ __launch_bounds__(256) void newmem_kernel(
    const float* __restrict__ X, const int* __restrict__ vis,
    const float* __restrict__ Mem, const int* __restrict__ lru_p,
    float* __restrict__ out) {
  const int r = blockIdx.x * 4 + (threadIdx.x >> 6);
  const int start = NPOS + lru_p[0] * (NNEG * BATCH);
  newmem_row(r, threadIdx.x & 63, X, vis, Mem, start, out);
}

extern "C" void kernel_launch(void* const* d_in, const int* in_sizes, int n_in,
                              void* d_out, int out_size, void* d_ws, size_t ws_size,
                              hipStream_t stream) {
  const float* x = (const float*)d_in[0];
  const int* y = (const int*)d_in[1];
  const int* visible = (const int*)d_in[2];
  const float* memory = (const float*)d_in[3];
  const int* lru = (const int*)d_in[4];
  float* out = (float*)d_out;

  const size_t OFF_Y = (size_t)BATCH * NPOS * NLEM;
  const size_t OFF_NOISE = OFF_Y + (size_t)BATCH * NPOS;
  const size_t OFF_MEM = OFF_NOISE + (size_t)BATCH * NNEG * NPOS;

  const size_t need = (size_t)NX_ELEM * 2;  // 2 MB bf16 scratch (x only)
  if (ws_size >= need) {
    unsigned short* xb = (unsigned short*)d_ws;
    prep_kernel<<<8720, 256, 0, stream>>>(x, y, visible, memory, lru, xb,
                                          out + OFF_Y, out + OFF_MEM);
    gemm_band2_kernel<<<512, 256, 0, stream>>>(xb, memory, out, out + OFF_NOISE);
  } else {
    gemm_conv_kernel<<<dim3(32, 256), 256, 0, stream>>>(x, memory, out, NLEM, 0);
    gemm_conv_kernel<<<dim3(32, 4), 256, 0, stream>>>(x, memory, out + OFF_NOISE, NPOS, NPOS);
    y_kernel<<<16, 256, 0, stream>>>(y, out + OFF_Y);
    newmem_kernel<<<NLEM / 4, 256, 0, stream>>>(x, visible, memory, lru, out + OFF_MEM);
  }
}

// Round 12
// 121.407 us; speedup vs baseline: 1.1578x; 1.0177x over previous
//
#include <hip/hip_runtime.h>
#include <hip/hip_bf16.h>
#include <cstdint>

#define NPOS 512
#define NNEG 512
#define BATCH 8
#define DDIM 128
#define NLEM 32768
#define NX_ELEM (BATCH * (NPOS + NNEG) * DDIM)  // 1048576
#define NM_ELEM (NLEM * DDIM)                   // 4194304

typedef __attribute__((ext_vector_type(4))) float f32x4;
typedef __attribute__((ext_vector_type(16))) float f32x16;
typedef __attribute__((ext_vector_type(8))) short short8;

__device__ __forceinline__ unsigned short f2bf(float f) {
  unsigned u = __float_as_uint(f);
  u = (u + 0x7FFFu + ((u >> 16) & 1u)) >> 16;
  return (unsigned short)u;
}

__device__ __forceinline__ short8 cvt8(f32x4 a0, f32x4 a1) {
  short8 w;
  w[0] = (short)f2bf(a0[0]); w[1] = (short)f2bf(a0[1]);
  w[2] = (short)f2bf(a0[2]); w[3] = (short)f2bf(a0[3]);
  w[4] = (short)f2bf(a1[0]); w[5] = (short)f2bf(a1[1]);
  w[6] = (short)f2bf(a1[2]); w[7] = (short)f2bf(a1[3]);
  return w;
}

__device__ __forceinline__ void async16(const void* g, void* l) {
  __builtin_amdgcn_global_load_lds(
      (const __attribute__((address_space(1))) unsigned int*)g,
      (__attribute__((address_space(3))) unsigned int*)l, 16, 0, 0);
}

// ---- shared newmem row logic (one wave per row, exact f32) ----
__device__ __forceinline__ void newmem_row(int r, int lane, const float* __restrict__ X,
                                           const int* __restrict__ vis,
                                           const float* __restrict__ Mem, int start,
                                           float* __restrict__ out) {
  const int d0 = lane, d1 = lane + 64;
  float v0, v1;
  if (r < NPOS) {
    const float s0 = Mem[(size_t)r * DDIM + d0];
    const float s1 = Mem[(size_t)r * DDIM + d1];
    float a0 = 0.f, a1 = 0.f;
#pragma unroll
    for (int b = 0; b < BATCH; ++b) {
      const float w = (float)vis[b * NPOS + r];
      const float* px = X + (size_t)(b * (NPOS + NNEG) + r) * DDIM;
      a0 += w * px[d0];
      a1 += w * px[d1];
    }
    v0 = 0.5f * s0 + 0.0625f * a0;
    v1 = 0.5f * s1 + 0.0625f * a1;
  } else if (r >= start && r < start + BATCH * NNEG) {
    const int q = r - start;
    const int b = q >> 9, n = q & 511;
    const float* px = X + (size_t)(b * (NPOS + NNEG) + NPOS + n) * DDIM;
    v0 = px[d0];
    v1 = px[d1];
  } else {
    v0 = Mem[(size_t)r * DDIM + d0];
    v1 = Mem[(size_t)r * DDIM + d1];
  }
  float s = v0 * v0 + v1 * v1;
#pragma unroll
  for (int off = 32; off; off >>= 1) s += __shfl_xor(s, off, 64);
  const float inv = 1.0f / fmaxf(sqrtf(s), 1e-12f);
  out[(size_t)r * DDIM + d0] = v0 * inv;
  out[(size_t)r * DDIM + d1] = v1 * inv;
}

// ==== prep (proven): convert all x + all memory, y, newmem ====
__global__ __launch_bounds__(256) void prep_kernel(
    const float* __restrict__ X, const int* __restrict__ y,
    const int* __restrict__ vis, const float* __restrict__ Mem,
    const int* __restrict__ lru_p, unsigned short* __restrict__ xb,
    unsigned short* __restrict__ mb, float* __restrict__ out_y,
    float* __restrict__ out_mem) {
  const int blk = blockIdx.x;
  if (blk < 512) {
    const size_t i = ((size_t)blk * 256 + threadIdx.x) * 8;
    *(short8*)(xb + i) = cvt8(*(const f32x4*)(X + i), *(const f32x4*)(X + i + 4));
  } else if (blk < 2560) {
    const size_t i = ((size_t)(blk - 512) * 256 + threadIdx.x) * 8;
    *(short8*)(mb + i) = cvt8(*(const f32x4*)(Mem + i), *(const f32x4*)(Mem + i + 4));
  } else if (blk < 2576) {
    const int i = (blk - 2560) * 256 + threadIdx.x;
    out_y[i] = (float)y[i];
  } else {
    const int r = (blk - 2576) * 4 + (threadIdx.x >> 6);
    const int start = NPOS + lru_p[0] * (NNEG * BATCH);
    newmem_row(r, threadIdx.x & 63, X, vis, Mem, start, out_mem);
  }
}

__device__ __forceinline__ void hoist_b(const short* Btile, short8 bfr[8][2],
                                        int wc, int la, int lb) {
#pragma unroll
  for (int kk = 0; kk < 8; ++kk)
#pragma unroll
    for (int n2 = 0; n2 < 2; ++n2) {
      const int row = wc * 64 + n2 * 32 + la;
      const int ss = ((kk * 2 + lb) ^ (row & 15)) * 8;
      bfr[kk][n2] = *(const short8*)&Btile[row * 128 + ss];
    }
}

__device__ __forceinline__ void tile_mfma(const short* Atile, const short8 bfr[8][2],
                                          f32x16 acc[2][2], int wr, int la, int lb) {
#pragma unroll
  for (int kk = 0; kk < 8; ++kk) {
    short8 af[2];
#pragma unroll
    for (int m2 = 0; m2 < 2; ++m2) {
      const int row = wr * 64 + m2 * 32 + la;
      const int ss = ((kk * 2 + lb) ^ (row & 15)) * 8;
      af[m2] = *(const short8*)&Atile[row * 128 + ss];
    }
#pragma unroll
    for (int m2 = 0; m2 < 2; ++m2)
#pragma unroll
      for (int n2 = 0; n2 < 2; ++n2)
        acc[m2][n2] = __builtin_amdgcn_mfma_f32_32x32x16_bf16(
            af[m2], bfr[kk][n2], acc[m2][n2], 0, 0, 0);
  }
}

__device__ __forceinline__ void store_acc(const f32x16 acc[2][2],
                                          float* __restrict__ C, int ldc, int m0,
                                          int n0c, int wr, int wc, int la, int lb) {
#pragma unroll
  for (int m2 = 0; m2 < 2; ++m2)
#pragma unroll
    for (int n2 = 0; n2 < 2; ++n2) {
      const int col = n0c + wc * 64 + n2 * 32 + la;
      const int rbase = m0 + wr * 64 + m2 * 32 + lb * 4;
#pragma unroll
      for (int r = 0; r < 16; ++r) {
        const int row = rbase + (r & 3) + 8 * (r >> 2);
        C[(size_t)row * ldc + col] = acc[m2][n2][r];
      }
    }
}

// ==== half-band persistent GEMM, 2 blocks/CU (64 KB LDS exactly) ====
// Block blk: band = blk>>1 (cols [band*128,+128)), h = blk&1 -> sim row
// panels K = h*16 + 0..15. B staged once through ldsA[1], hoisted to regs.
// Blocks 0..127 additionally compute one noise tile at the tail.
__global__ __launch_bounds__(256, 2) void gemm_band2_kernel(
    const unsigned short* __restrict__ Xb, const unsigned short* __restrict__ Mb,
    float* __restrict__ Csim, float* __restrict__ Cnoise) {
  __shared__ short ldsA[2][128 * 128];  // exactly 64 KB

  const int t = threadIdx.x;
  const int lane = t & 63, wv = t >> 6;
  const int rl = lane >> 4, slot = lane & 15;
  const int wr = wv >> 1, wc = wv & 1;
  const int la = lane & 31, lb = lane >> 5;
  const int blk = blockIdx.x;
  const int band = blk >> 1, h = blk & 1;
  const int n0 = band * 128;

  auto stage_tile = [&](short* dst, const unsigned short* src, int rowbase) {
#pragma unroll
    for (int i = 0; i < 8; ++i) {
      const int rowb = wv * 32 + i * 4;  // wave-uniform base row
      const int row = rowb + rl;
      const int ss = slot ^ (row & 15);  // inverse-swizzled source (involution)
      async16(src + (size_t)(rowbase + row) * DDIM + ss * 8, &dst[rowb * 128]);
    }
  };

  // ---- prologue: B through ldsA[1]; first A panel into ldsA[0] ----
  stage_tile(ldsA[1], Mb, n0);
  {
    const int K0 = h * 16;
    stage_tile(ldsA[0], Xb, (K0 >> 2) * 1024 + (K0 & 3) * 128);
  }
  asm volatile("s_waitcnt vmcnt(0)" ::: "memory");
  __builtin_amdgcn_s_barrier();
  __builtin_amdgcn_sched_barrier(0);

  short8 bfr[8][2];
  hoist_b(ldsA[1], bfr, wc, la, lb);  // B -> 32 VGPR
  // all hoist ds_reads must finish before k=0 DMAs into ldsA[1]
  asm volatile("s_waitcnt lgkmcnt(0)" ::: "memory");
  __builtin_amdgcn_s_barrier();
  __builtin_amdgcn_sched_barrier(0);

  int p = 0;
  for (int k = 0; k < 16; ++k) {
    // stage next panel BEFORE this step's stores (counted-vmcnt guarantee)
    if (k + 1 < 16) {
      const int K = h * 16 + k + 1;
      stage_tile(ldsA[p ^ 1], Xb, (K >> 2) * 1024 + (K & 3) * 128);
    }

    f32x16 acc[2][2] = {};
    tile_mfma(ldsA[p], bfr, acc, wr, la, lb);
    store_acc(acc, Csim, NLEM, (h * 16 + k) * 128, n0, wr, wc, la, lb);

    // vmcnt(60) < 64 stores issued after the 8 staging loads => loads
    // retired; ~60 stores keep draining across the barrier.
    asm volatile("s_waitcnt vmcnt(60)" ::: "memory");
    __builtin_amdgcn_s_barrier();
    __builtin_amdgcn_sched_barrier(0);
    p ^= 1;
  }

  // ---- noise tail: blocks 0..127 each do one 128x128 noise tile ----
  if (blk < 128) {
    const int rp = blk >> 2, cb = blk & 3;  // row panel 0..31, col band 0..3
    stage_tile(ldsA[p ^ 1], Xb, (rp >> 2) * 1024 + 512 + (rp & 3) * 128);
    stage_tile(ldsA[p], Mb, cb * 128);
    asm volatile("s_waitcnt vmcnt(0)" ::: "memory");
    __builtin_amdgcn_s_barrier();
    __builtin_amdgcn_sched_barrier(0);
    short8 bfr2[8][2];
    hoist_b(ldsA[p], bfr2, wc, la, lb);
    f32x16 acc[2][2] = {};
    tile_mfma(ldsA[p ^ 1], bfr2, acc, wr, la, lb);
    store_acc(acc, Cnoise, NPOS, rp * 128, cb * 128, wr, wc, la, lb);
  }
}

// ================= fallback path (used only if ws too small) ====
__global__ __launch_bounds__(256) void gemm_conv_kernel(
    const float* __restrict__ X, const float* __restrict__ Bm,
    float* __restrict__ C, int ldc, int a_off) {
  __shared__ short lds[2 * 128 * 128];
  short* ldsA = lds;
  short* ldsB = lds + 128 * 128;
  const int t = threadIdx.x;
  const int m0 = blockIdx.x * 128;
  const int n0 = blockIdx.y * 128;
  const int slot = t & 15;
  const int rsub = t >> 4;
#pragma unroll
  for (int it = 0; it < 8; ++it) {
    const int row = it * 16 + rsub;
    const int gr = m0 + row;
    const int xrow = ((gr >> 9) << 10) + (gr & 511) + a_off;
    const f32x4* pa = (const f32x4*)(X + (size_t)xrow * DDIM + slot * 8);
    const f32x4* pb = (const f32x4*)(Bm + (size_t)(n0 + row) * DDIM + slot * 8);
    short8 wa = cvt8(pa[0], pa[1]);
    short8 wb = cvt8(pb[0], pb[1]);
    const int ss = (slot ^ (row & 15)) * 8;
    *(short8*)&ldsA[row * 128 + ss] = wa;
    *(short8*)&ldsB[row * 128 + ss] = wb;
  }
  __syncthreads();
  const int lane = t & 63;
  const int wv = t >> 6;
  const int wr = wv >> 1, wc = wv & 1;
  const int la = lane & 31, lb = lane >> 5;
  short8 bfr[8][2];
  hoist_b(ldsB, bfr, wc, la, lb);
  f32x16 acc[2][2] = {};
  tile_mfma(ldsA, bfr, acc, wr, la, lb);
  store_acc(acc, C, ldc, m0, n0, wr, wc, la, lb);
}

__global__ void y_kernel(const int* __restrict__ y, float* __restrict__ out) {
  const int i = blockIdx.x * blockDim.x + threadIdx.x;
  if (i < BATCH * NPOS) out[i] = (float)y[i];
}

__global__ __launch_bounds__(256) void newmem_kernel(
    const float* __restrict__ X, const int* __restrict__ vis,
    const float* __restrict__ Mem, const int* __restrict__ lru_p,
    float* __restrict__ out) {
  const int r = blockIdx.x * 4 + (threadIdx.x >> 6);
  const int start = NPOS + lru_p[0] * (NNEG * BATCH);
  newmem_row(r, threadIdx.x & 63, X, vis, Mem, start, out);
}

extern "C" void kernel_launch(void* const* d_in, const int* in_sizes, int n_in,
                              void* d_out, int out_size, void* d_ws, size_t ws_size,
                              hipStream_t stream) {
  const float* x = (const float*)d_in[0];
  const int* y = (const int*)d_in[1];
  const int* visible = (const int*)d_in[2];
  const float* memory = (const float*)d_in[3];
  const int* lru = (const int*)d_in[4];
  float* out = (float*)d_out;

  const size_t OFF_Y = (size_t)BATCH * NPOS * NLEM;
  const size_t OFF_NOISE = OFF_Y + (size_t)BATCH * NPOS;
  const size_t OFF_MEM = OFF_NOISE + (size_t)BATCH * NNEG * NPOS;

  const size_t need = (size_t)(NX_ELEM + NM_ELEM) * 2;  // 10.5 MB bf16 scratch
  if (ws_size >= need) {
    unsigned short* xb = (unsigned short*)d_ws;
    unsigned short* mb = xb + NX_ELEM;
    prep_kernel<<<10768, 256, 0, stream>>>(
        x, y, visible, memory, lru, xb, mb, out + OFF_Y, out + OFF_MEM);
    gemm_band2_kernel<<<512, 256, 0, stream>>>(xb, mb, out, out + OFF_NOISE);
  } else {
    gemm_conv_kernel<<<dim3(32, 256), 256, 0, stream>>>(x, memory, out, NLEM, 0);
    gemm_conv_kernel<<<dim3(32, 4), 256, 0, stream>>>(x, memory, out + OFF_NOISE, NPOS, NPOS);
    y_kernel<<<16, 256, 0, stream>>>(y, out + OFF_Y);
    newmem_kernel<<<NLEM / 4, 256, 0, stream>>>(x, visible, memory, lru, out + OFF_MEM);
  }
}